// Round 17
// baseline (474.730 us; speedup 1.0000x reference)
//
#include <hip/hip_runtime.h>
#include <hip/hip_bf16.h>
#include <hip/hip_fp16.h>

typedef float f32x4 __attribute__((ext_vector_type(4)));
typedef float f32x2 __attribute__((ext_vector_type(2)));
typedef short s16x8 __attribute__((ext_vector_type(8)));
typedef unsigned short u16;
typedef unsigned char u8;

#define LOG2F 0.6931471805599453f
#define LDA 136   // padded LDS row stride (bf16 elems): 2-way bank alias only (free)
#define BNG 512   // bnmid grid (also its partial count)

__device__ __forceinline__ u16 f2bf(float f) {               // RNE f32->bf16
  unsigned u = __float_as_uint(f);
  u += 0x7fffu + ((u >> 16) & 1u);
  return (u16)(u >> 16);
}
__device__ __forceinline__ float bf2f(u16 h){ return __uint_as_float((unsigned)h << 16); }
__device__ __forceinline__ float bflo(unsigned u){ return __uint_as_float(u << 16); }
__device__ __forceinline__ float bfhi(unsigned u){ return __uint_as_float(u & 0xffff0000u); }

// fp8 e4m3 (OCP on gfx950) pack/unpack via hardware converts
__device__ __forceinline__ void fp8dec(unsigned u, float* a){   // 4 fp8 bytes -> 4 f32
  f32x2 lo = __builtin_amdgcn_cvt_pk_f32_fp8((int)u, false);
  f32x2 hi = __builtin_amdgcn_cvt_pk_f32_fp8((int)u, true);
  a[0] = lo[0]; a[1] = lo[1]; a[2] = hi[0]; a[3] = hi[1];
}
__device__ __forceinline__ unsigned fp8enc4(float a0, float a1, float a2, float a3){
  int r = __builtin_amdgcn_cvt_pk_fp8_f32(a0, a1, 0, false);
  r = __builtin_amdgcn_cvt_pk_fp8_f32(a2, a3, r, true);
  return (unsigned)r;
}
__device__ __forceinline__ u8 fp8enc1(float v){
  return (u8)(__builtin_amdgcn_cvt_pk_fp8_f32(v, v, 0, false) & 0xff);
}
// fast softplus(-s) via hw exp2/log2 (v_exp_f32 = 2^x, v_log_f32 = log2 x)
__device__ __forceinline__ float softplus_neg(float s){
  float e = __builtin_amdgcn_exp2f(-fabsf(s) * 1.442695040888963f);
  return fmaxf(-s, 0.f) + __builtin_amdgcn_logf(1.f + e) * 0.6931471805599453f;
}

// ---- convert+transpose weights to bf16: Wt[m][c][k] = W_m[k][c] ----
__global__ void convw(const float* __restrict__ gW, const float* __restrict__ Wlin,
                      u16* __restrict__ Wt, int L) {
  int idx = blockIdx.x * 256 + threadIdx.x;
  int total = (L + 2) * 16384;
  if (idx >= total) return;
  int m = idx >> 14, rem = idx & 16383, c = rem >> 7, k = rem & 127;
  float v;
  if (m < L)           v = gW[(size_t)m * 16384 + k * 128 + c];
  else if (m == L)     v = Wlin[k * 128 + c];            // top half (root)
  else                 v = Wlin[(128 + k) * 128 + c];    // bottom half (features)
  Wt[idx] = f2bf(v);
}

// features f32 -> bf16 (for GEMM) + fp8 (for gather)
__global__ void convf(const float* __restrict__ in, u16* __restrict__ outb,
                      u8* __restrict__ outq, int n4) {
  int stride = gridDim.x * blockDim.x;
  for (int i = blockIdx.x * blockDim.x + threadIdx.x; i < n4; i += stride) {
    float4 v = ((const float4*)in)[i];
    ushort4 o; o.x = f2bf(v.x); o.y = f2bf(v.y); o.z = f2bf(v.z); o.w = f2bf(v.w);
    ((ushort4*)outb)[i] = o;
    ((unsigned*)outq)[i] = fp8enc4(v.x, v.y, v.z, v.w);
  }
}

// ---------------- CSR build (dst -> list of src), deterministic ----------------
__global__ void cntk(int* __restrict__ cnt, const int* __restrict__ key, int E) {
  int e = blockIdx.x * 256 + threadIdx.x;
  if (e < E) atomicAdd(&cnt[key[e]], 1);
}

__global__ void scanA(const int* __restrict__ cnt, int* __restrict__ excl,
                      int* __restrict__ bsum, int N) {
  __shared__ int tmp[256];
  int i = blockIdx.x * 256 + threadIdx.x;
  int v = (i < N) ? cnt[i] : 0;
  tmp[threadIdx.x] = v;
  __syncthreads();
  for (int off = 1; off < 256; off <<= 1) {
    int t = (threadIdx.x >= off) ? tmp[threadIdx.x - off] : 0;
    __syncthreads();
    tmp[threadIdx.x] += t;
    __syncthreads();
  }
  if (i < N) excl[i] = tmp[threadIdx.x] - v;
  if (threadIdx.x == 255) bsum[blockIdx.x] = tmp[255];
}

__global__ void scanB(const int* __restrict__ bsum, int* __restrict__ boff,
                      int nb, int* __restrict__ rowptrN) {
  __shared__ int tmp[256];
  __shared__ int carry;
  if (threadIdx.x == 0) carry = 0;
  __syncthreads();
  for (int base = 0; base < nb; base += 256) {
    int i = base + threadIdx.x;
    int v = (i < nb) ? bsum[i] : 0;
    tmp[threadIdx.x] = v;
    __syncthreads();
    for (int off = 1; off < 256; off <<= 1) {
      int t = (threadIdx.x >= off) ? tmp[threadIdx.x - off] : 0;
      __syncthreads();
      tmp[threadIdx.x] += t;
      __syncthreads();
    }
    if (i < nb) boff[i] = carry + tmp[threadIdx.x] - v;
    __syncthreads();
    if (threadIdx.x == 255) carry += tmp[255];
    __syncthreads();
  }
  if (threadIdx.x == 0) *rowptrN = carry;
}

__global__ void scanC(const int* __restrict__ excl, const int* __restrict__ boff,
                      int* __restrict__ rowptr, int* __restrict__ cursor, int N) {
  int i = blockIdx.x * 256 + threadIdx.x;
  if (i < N) {
    int r = excl[i] + boff[blockIdx.x];
    rowptr[i] = r; cursor[i] = r;
  }
}

__global__ void fillk(const int* __restrict__ key, const int* __restrict__ val,
                      int* __restrict__ cursor, int* __restrict__ out, int E) {
  int e = blockIdx.x * 256 + threadIdx.x;
  if (e < E) {
    int pos = atomicAdd(&cursor[key[e]], 1);
    out[pos] = val[e];
  }
}

// wave-parallel per-node sort (bitonic in registers) + dstj fill (merged expk)
__global__ __launch_bounds__(256) void sortk(const int* __restrict__ rowptr,
                                             int* __restrict__ arr,
                                             int* __restrict__ dstj, int N) {
  int wave = threadIdx.x >> 6, lane = threadIdx.x & 63;
  int n = blockIdx.x * 4 + wave;
  if (n >= N) return;
  int lo = rowptr[n], hi = rowptr[n + 1];
  int d = hi - lo;
  for (int j = lo + lane; j < hi; j += 64) dstj[j] = n;
  if (d <= 1) return;
  if (d <= 64) {
    int v = (lane < d) ? arr[lo + lane] : 0x7fffffff;
#pragma unroll
    for (int k = 2; k <= 64; k <<= 1) {
#pragma unroll
      for (int jj = k >> 1; jj > 0; jj >>= 1) {
        int partner = __shfl_xor(v, jj);
        bool up = ((lane & k) == 0);
        bool keepmin = (((lane & jj) == 0) == up);
        v = keepmin ? min(v, partner) : max(v, partner);
      }
    }
    if (lane < d) arr[lo + lane] = v;
  } else if (lane == 0) {
    for (int i = lo + 1; i < hi; i++) {
      int v = arr[i];
      int j = i - 1;
      while (j >= lo && arr[j] > v) { arr[j + 1] = arr[j]; j--; }
      arr[j + 1] = v;
    }
  }
}

// YZ[n] = interleaved {y[n] 8B | y[perm[n]] 8B} per lane16 (row 256B), raw fp8 copy
__global__ void zk(const u8* __restrict__ Yb, const int* __restrict__ perm,
                   u8* __restrict__ YZ, int N) {
  int idx = blockIdx.x * 256 + threadIdx.x;
  if (idx >= N * 16) return;
  int n = idx >> 4, l = idx & 15;
  const uint2* y2 = (const uint2*)Yb;
  uint2 a = y2[(size_t)n * 16 + l];
  uint2 b = y2[(size_t)perm[n] * 16 + l];
  uint4 o; o.x = a.x; o.y = a.y; o.z = b.x; o.w = b.y;
  ((uint4*)YZ)[idx] = o;
}

// ---------------- GIN aggregation from fp8 rows (1 node / 16-lane group) ----------
template<int BN>
__global__ __launch_bounds__(256) void aggk0(
    const u8* __restrict__ emb, u16* __restrict__ out,
    const int* __restrict__ rowptr, const int* __restrict__ col,
    const float* __restrict__ epsp, int l,
    const float* __restrict__ sc2, const float* __restrict__ sh2, int N) {
  int tid = threadIdx.x;
  int grp = tid >> 4, lane16 = tid & 15;
  int n = blockIdx.x * 16 + grp;
  if (n >= N) return;
  int lo = rowptr[n], hi = rowptr[n + 1];
  const uint2* embq = (const uint2*)emb;       // row = 16 uint2 (128B)
  float sc[8], sh[8];
  if (BN) {
#pragma unroll
    for (int k = 0; k < 8; k++) { sc[k] = sc2[lane16 * 8 + k]; sh[k] = sh2[lane16 * 8 + k]; }
  }
  float s[8] = {0.f,0.f,0.f,0.f,0.f,0.f,0.f,0.f};
#define ACCD(v) { float t[8]; fp8dec(v.x, t); fp8dec(v.y, t + 4); \
                  _Pragma("unroll") for (int k = 0; k < 8; k++) \
                    s[k] += BN ? fmaxf(fmaf(t[k], sc[k], sh[k]), 0.f) : t[k]; }
  int j = lo;
  for (; j + 4 <= hi; j += 4) {
    int c0 = col[j], c1 = col[j+1], c2 = col[j+2], c3 = col[j+3];
    uint2 v0 = embq[(size_t)c0 * 16 + lane16];
    uint2 v1 = embq[(size_t)c1 * 16 + lane16];
    uint2 v2 = embq[(size_t)c2 * 16 + lane16];
    uint2 v3 = embq[(size_t)c3 * 16 + lane16];
    ACCD(v0); ACCD(v1); ACCD(v2); ACCD(v3);
  }
  for (; j < hi; j++) {
    uint2 v = embq[(size_t)col[j] * 16 + lane16];
    ACCD(v);
  }
#undef ACCD
  float e1 = 1.f + epsp[l];
  {
    uint2 hv = embq[(size_t)n * 16 + lane16];
    float t[8]; fp8dec(hv.x, t); fp8dec(hv.y, t + 4);
#pragma unroll
    for (int k = 0; k < 8; k++) {
      float g = BN ? fmaxf(fmaf(t[k], sc[k], sh[k]), 0.f) : t[k];
      s[k] = fmaf(e1, g, s[k]);
    }
  }
  uint4 o;
  o.x = ((unsigned)f2bf(s[1]) << 16) | (unsigned)f2bf(s[0]);
  o.y = ((unsigned)f2bf(s[3]) << 16) | (unsigned)f2bf(s[2]);
  o.z = ((unsigned)f2bf(s[5]) << 16) | (unsigned)f2bf(s[4]);
  o.w = ((unsigned)f2bf(s[7]) << 16) | (unsigned)f2bf(s[6]);
  ((uint4*)out)[(size_t)n * 16 + lane16] = o;
}

// ---------------- GEMM: out[n][c] = cvt(g(A[n]) @ Wt^T + bias) ----------------
// infmt: 0 bf16 in, 2 fp8 in. optional g(x)=relu(bnsc*x+bnsh). fmt: 0 bf16 out, 2 fp8 out.
__global__ __launch_bounds__(256) void gemm_k128(
    const void* __restrict__ inv, const u16* __restrict__ Wt, const float* __restrict__ bias,
    void* __restrict__ outv, float* __restrict__ pS, float* __restrict__ pQ, int GP,
    int ostride, int infmt, int fmt,
    const float* __restrict__ bnsc, const float* __restrict__ bnsh, int nrows) {
  __shared__ u16 Alds[64 * LDA];
  __shared__ u16 Wlds[128 * LDA];
  int tid = threadIdx.x;
  int r0 = blockIdx.x * 64;
#pragma unroll
  for (int i = 0; i < 8; i++) {
    int idx = tid + i * 256;
    int r = idx >> 4, o = idx & 15;
    uint4 v = *(const uint4*)(Wt + (size_t)r * 128 + o * 8);
    *(uint4*)(&Wlds[r * LDA + o * 8]) = v;
  }
  {
    int o = tid & 15;                 // channel group fixed per thread
    float sc[8], sh[8];
    if (bnsc) {
#pragma unroll
      for (int k = 0; k < 8; k++) { sc[k] = bnsc[o * 8 + k]; sh[k] = bnsh[o * 8 + k]; }
    }
#pragma unroll
    for (int i = 0; i < 4; i++) {
      int idx = tid + i * 256;
      int r = idx >> 4;
      uint4 v;
      if (infmt == 0 && !bnsc) {      // fast path: raw bf16 copy
        if (r0 + r < nrows) v = ((const uint4*)((const u16*)inv + (size_t)(r0 + r) * 128))[o];
        else { v.x = 0; v.y = 0; v.z = 0; v.w = 0; }
      } else {
        float t[8] = {0.f,0.f,0.f,0.f,0.f,0.f,0.f,0.f};
        if (r0 + r < nrows) {
          if (infmt == 0) {
            uint4 b = ((const uint4*)((const u16*)inv + (size_t)(r0 + r) * 128))[o];
            t[0] = bflo(b.x); t[1] = bfhi(b.x); t[2] = bflo(b.y); t[3] = bfhi(b.y);
            t[4] = bflo(b.z); t[5] = bfhi(b.z); t[6] = bflo(b.w); t[7] = bfhi(b.w);
          } else {
            uint2 q = *(const uint2*)((const u8*)inv + (size_t)(r0 + r) * 128 + o * 8);
            fp8dec(q.x, t); fp8dec(q.y, t + 4);
          }
          if (bnsc) {
#pragma unroll
            for (int k = 0; k < 8; k++) t[k] = fmaxf(fmaf(t[k], sc[k], sh[k]), 0.f);
          }
        }
        v.x = ((unsigned)f2bf(t[1]) << 16) | (unsigned)f2bf(t[0]);
        v.y = ((unsigned)f2bf(t[3]) << 16) | (unsigned)f2bf(t[2]);
        v.z = ((unsigned)f2bf(t[5]) << 16) | (unsigned)f2bf(t[4]);
        v.w = ((unsigned)f2bf(t[7]) << 16) | (unsigned)f2bf(t[6]);
      }
      *(uint4*)(&Alds[r * LDA + o * 8]) = v;
    }
  }
  __syncthreads();
  int lane = tid & 63;
  int wv = tid >> 6;
  int cbase = wv * 32;
  int lr = lane & 15;
  int kg = lane >> 4;
  f32x4 acc[4][2] = {};
#pragma unroll
  for (int kc = 0; kc < 4; kc++) {
    int koff = kc * 32 + kg * 8;
    s16x8 a[4], b[2];
#pragma unroll
    for (int rt = 0; rt < 4; rt++)
      a[rt] = *reinterpret_cast<const s16x8*>(&Alds[(rt * 16 + lr) * LDA + koff]);
#pragma unroll
    for (int ct = 0; ct < 2; ct++)
      b[ct] = *reinterpret_cast<const s16x8*>(&Wlds[(cbase + ct * 16 + lr) * LDA + koff]);
#pragma unroll
    for (int rt = 0; rt < 4; rt++)
#pragma unroll
      for (int ct = 0; ct < 2; ct++)
        acc[rt][ct] = __builtin_amdgcn_mfma_f32_16x16x32_bf16(a[rt], b[ct], acc[rt][ct], 0, 0, 0);
  }
#pragma unroll
  for (int ct = 0; ct < 2; ct++) {
    int c = cbase + ct * 16 + lr;
    float bv = bias ? bias[c] : 0.f;
    float ls = 0.f, lq = 0.f;
#pragma unroll
    for (int rt = 0; rt < 4; rt++)
#pragma unroll
      for (int j = 0; j < 4; j++) {
        int row = r0 + rt * 16 + kg * 4 + j;
        if (row < nrows) {
          float v = acc[rt][ct][j] + bv;
          size_t idx = (size_t)row * ostride + c;
          if (fmt == 0)      ((u16*)outv)[idx] = f2bf(v);
          else               ((u8*)outv)[idx] = fp8enc1(v);
          ls += v; lq += v * v;
        }
      }
    if (pS) {
      ls += __shfl_xor(ls, 16); lq += __shfl_xor(lq, 16);
      ls += __shfl_xor(ls, 32); lq += __shfl_xor(lq, 32);
      if (kg == 0) {
        pS[(size_t)c * GP + blockIdx.x] = ls;
        pQ[(size_t)c * GP + blockIdx.x] = lq;
      }
    }
  }
}

// finalize BN params from per-block partials
__global__ __launch_bounds__(256) void finbn(
    const float* __restrict__ pS, const float* __restrict__ pQ, int G, int GP,
    const float* __restrict__ g, const float* __restrict__ b,
    float* __restrict__ scale, float* __restrict__ shift, float invN) {
  int c = blockIdx.x;
  int tid = threadIdx.x;
  float s = 0.f, q = 0.f;
  for (int i = tid; i < G; i += 256) {
    s += pS[(size_t)c * GP + i];
    q += pQ[(size_t)c * GP + i];
  }
  __shared__ float rs[256], rq[256];
  rs[tid] = s; rq[tid] = q;
  __syncthreads();
  for (int off = 128; off > 0; off >>= 1) {
    if (tid < off) { rs[tid] += rs[tid + off]; rq[tid] += rq[tid + off]; }
    __syncthreads();
  }
  if (tid == 0) {
    float m = rs[0] * invN;
    float v = rq[0] * invN - m * m;
    float sc = g[c] * rsqrtf(v + 1e-5f);
    scale[c] = sc;
    shift[c] = b[c] - m * sc;
  }
}

// y1 = fp8(relu(scale1*x+shift1)) + per-block column partials of y1
__global__ __launch_bounds__(256) void bnmid(
    const u16* __restrict__ x, u8* __restrict__ yq,
    const float* __restrict__ scale1, const float* __restrict__ shift1,
    float* __restrict__ pS, float* __restrict__ pQ, int n4) {
  int tid = threadIdx.x;
  int i0 = blockIdx.x * 256 + tid;
  int stride = gridDim.x * 256;
  int c4 = i0 & 31;
  float sc[4], sh[4];
#pragma unroll
  for (int k = 0; k < 4; k++) {
    sc[k] = scale1[c4 * 4 + k];
    sh[k] = shift1[c4 * 4 + k];
  }
  float ls[4] = {0.f,0.f,0.f,0.f}, lq[4] = {0.f,0.f,0.f,0.f};
  for (int i = i0; i < n4; i += stride) {
    ushort4 hv = ((const ushort4*)x)[i];
    float v0 = fmaxf(fmaf(bf2f(hv.x), sc[0], sh[0]), 0.f);
    float v1 = fmaxf(fmaf(bf2f(hv.y), sc[1], sh[1]), 0.f);
    float v2 = fmaxf(fmaf(bf2f(hv.z), sc[2], sh[2]), 0.f);
    float v3 = fmaxf(fmaf(bf2f(hv.w), sc[3], sh[3]), 0.f);
    ((unsigned*)yq)[i] = fp8enc4(v0, v1, v2, v3);
    ls[0] += v0; ls[1] += v1; ls[2] += v2; ls[3] += v3;
    lq[0] += v0*v0; lq[1] += v1*v1; lq[2] += v2*v2; lq[3] += v3*v3;
  }
  __shared__ float red[256][8];
#pragma unroll
  for (int k = 0; k < 4; k++) { red[tid][k] = ls[k]; red[tid][4+k] = lq[k]; }
  __syncthreads();
  for (int off = 128; off >= 32; off >>= 1) {
    if (tid < off)
#pragma unroll
      for (int s = 0; s < 8; s++) red[tid][s] += red[tid + off][s];
    __syncthreads();
  }
  if (tid < 32) {
#pragma unroll
    for (int k = 0; k < 4; k++) {
      pS[(size_t)(tid * 4 + k) * BNG + blockIdx.x] = red[tid][k];
      pQ[(size_t)(tid * 4 + k) * BNG + blockIdx.x] = red[tid][4 + k];
    }
  }
}

// Af[n] = interleaved {pos 8B | neg 8B} per lane16 (row 256B), fp8.
// ONE 16B load/lane/edge from interleaved YZ; 4-edge unroll.
__global__ __launch_bounds__(256) void aggab(
    const u8* __restrict__ YZ, u8* __restrict__ Af,
    const int* __restrict__ rowptr, const int* __restrict__ col, int N) {
  int tid = threadIdx.x;
  int grp = tid >> 4, lane16 = tid & 15;
  int n = blockIdx.x * 16 + grp;
  if (n >= N) return;
  int lo = rowptr[n], hi = rowptr[n + 1];
  const uint4* yz = (const uint4*)YZ;          // row = 16 uint4 (y8|z8 per lane)
  uint4* af = (uint4*)Af;
  if (hi == lo) {                              // deg 0: {y[n], y[perm[n]]} = YZ row
    af[(size_t)n * 16 + lane16] = yz[(size_t)n * 16 + lane16];
    return;
  }
  float ap[8] = {0.f,0.f,0.f,0.f,0.f,0.f,0.f,0.f};
  float an[8] = {0.f,0.f,0.f,0.f,0.f,0.f,0.f,0.f};
#define ACCD(v) { float t[8], u[8]; \
                  fp8dec(v.x, t); fp8dec(v.y, t + 4); \
                  fp8dec(v.z, u); fp8dec(v.w, u + 4); \
                  _Pragma("unroll") for (int k = 0; k < 8; k++) { ap[k] += t[k]; an[k] += u[k]; } }
  int j = lo;
  for (; j + 4 <= hi; j += 4) {
    int c0 = col[j], c1 = col[j+1], c2 = col[j+2], c3 = col[j+3];
    uint4 v0 = yz[(size_t)c0 * 16 + lane16];
    uint4 v1 = yz[(size_t)c1 * 16 + lane16];
    uint4 v2 = yz[(size_t)c2 * 16 + lane16];
    uint4 v3 = yz[(size_t)c3 * 16 + lane16];
    ACCD(v0); ACCD(v1); ACCD(v2); ACCD(v3);
  }
  for (; j < hi; j++) {
    uint4 v = yz[(size_t)col[j] * 16 + lane16];
    ACCD(v);
  }
#undef ACCD
  float inv = 1.f / (float)(hi - lo);
  uint4 o;
  o.x = fp8enc4(ap[0]*inv, ap[1]*inv, ap[2]*inv, ap[3]*inv);
  o.y = fp8enc4(ap[4]*inv, ap[5]*inv, ap[6]*inv, ap[7]*inv);
  o.z = fp8enc4(an[0]*inv, an[1]*inv, an[2]*inv, an[3]*inv);
  o.w = fp8enc4(an[4]*inv, an[5]*inv, an[6]*inv, an[7]*inv);
  af[(size_t)n * 16 + lane16] = o;
}

// flat dst-major edge scoring: 16 lanes/edge, 4-edge unroll, f32 math;
// Af[src] interleaved fp8 = ONE 16B load/lane; B[dst] bf16 = ONE 16B load
__global__ __launch_bounds__(256) void edgek(
    const u8* __restrict__ Af, const u16* __restrict__ Bf,
    const int* __restrict__ col, const int* __restrict__ dstj,
    const float* __restrict__ Wu, const float* __restrict__ bu,
    int E, double* __restrict__ acc) {
  int tid = threadIdx.x;
  int lane16 = tid & 15;
  float w[8];
#pragma unroll
  for (int k = 0; k < 8; k++) w[k] = Wu[lane16 * 8 + k];
  float bias = bu[0];
  float lp = 0.f, ln = 0.f;
  int g = (blockIdx.x * 256 + tid) >> 4;
  int ng = (gridDim.x * 256) >> 4;
  int per = (E + ng - 1) / ng;
  int j0 = g * per;
  int j1 = min(E, j0 + per);
#define EDGE(jj, SP, SN) { \
    int s = col[jj]; int d = dstj[jj]; \
    uint4 av = *(const uint4*)(Af + (size_t)s * 256 + lane16 * 16); \
    uint4 bv = *(const uint4*)(Bf + (size_t)d * 128 + lane16 * 8); \
    float a8[8], n8[8]; \
    fp8dec(av.x, a8); fp8dec(av.y, a8 + 4); \
    fp8dec(av.z, n8); fp8dec(av.w, n8 + 4); \
    float bb[8] = {bflo(bv.x), bfhi(bv.x), bflo(bv.y), bfhi(bv.y), \
                   bflo(bv.z), bfhi(bv.z), bflo(bv.w), bfhi(bv.w)}; \
    _Pragma("unroll") \
    for (int i = 0; i < 8; i++) { \
      SP = fmaf(fmaxf(a8[i] + bb[i], 0.f), w[i], SP); \
      SN = fmaf(fmaxf(n8[i] + bb[i], 0.f), w[i], SN); \
    } }
  int j = j0;
  for (; j + 4 <= j1; j += 4) {
    float sp0 = 0.f, sn0 = 0.f, sp1 = 0.f, sn1 = 0.f;
    float sp2 = 0.f, sn2 = 0.f, sp3 = 0.f, sn3 = 0.f;
    EDGE(j, sp0, sn0);
    EDGE(j + 1, sp1, sn1);
    EDGE(j + 2, sp2, sn2);
    EDGE(j + 3, sp3, sn3);
#pragma unroll
    for (int m = 1; m < 16; m <<= 1) {
      sp0 += __shfl_xor(sp0, m); sn0 += __shfl_xor(sn0, m);
      sp1 += __shfl_xor(sp1, m); sn1 += __shfl_xor(sn1, m);
      sp2 += __shfl_xor(sp2, m); sn2 += __shfl_xor(sn2, m);
      sp3 += __shfl_xor(sp3, m); sn3 += __shfl_xor(sn3, m);
    }
    if (lane16 == 0) {
      float a0 = sp0 + bias, b0 = sn0 + bias;
      float a1 = sp1 + bias, b1 = sn1 + bias;
      float a2 = sp2 + bias, b2 = sn2 + bias;
      float a3 = sp3 + bias, b3 = sn3 + bias;
      lp += (LOG2F - softplus_neg(a0)) + (LOG2F - softplus_neg(a1))
          + (LOG2F - softplus_neg(a2)) + (LOG2F - softplus_neg(a3));
      ln += (softplus_neg(b0) + b0 - LOG2F) + (softplus_neg(b1) + b1 - LOG2F)
          + (softplus_neg(b2) + b2 - LOG2F) + (softplus_neg(b3) + b3 - LOG2F);
    }
  }
  for (; j < j1; j++) {
    float sp = 0.f, sn = 0.f;
    EDGE(j, sp, sn);
#pragma unroll
    for (int m = 1; m < 16; m <<= 1) {
      sp += __shfl_xor(sp, m); sn += __shfl_xor(sn, m);
    }
    if (lane16 == 0) {
      float a = sp + bias, b = sn + bias;
      lp += LOG2F - softplus_neg(a);
      ln += softplus_neg(b) + b - LOG2F;
    }
  }
#undef EDGE
  __shared__ float rp[256], rn[256];
  rp[tid] = lp; rn[tid] = ln;
  __syncthreads();
  for (int off = 128; off > 0; off >>= 1) {
    if (tid < off) { rp[tid] += rp[tid + off]; rn[tid] += rn[tid + off]; }
    __syncthreads();
  }
  if (tid == 0) {
    unsafeAtomicAdd(&acc[0], (double)rp[0]);
    unsafeAtomicAdd(&acc[1], (double)rn[0]);
  }
}

__global__ void fink(const double* __restrict__ acc, float* __restrict__ out, int E) {
  out[0] = (float)((acc[1] - acc[0]) / (double)E);
}

extern "C" void kernel_launch(void* const* d_in, const int* in_sizes, int n_in,
                              void* d_out, int out_size, void* d_ws, size_t ws_size,
                              hipStream_t stream) {
  const float* features = (const float*)d_in[0];
  const float* gin_W    = (const float*)d_in[1];
  const float* gin_b    = (const float*)d_in[2];
  const float* gin_eps  = (const float*)d_in[3];
  const float* bn1_g    = (const float*)d_in[4];
  const float* bn1_b    = (const float*)d_in[5];
  const float* bn2_g    = (const float*)d_in[6];
  const float* bn2_b    = (const float*)d_in[7];
  // d_in[8]=Wz, d_in[9]=bz: dead code in reference (m1 deleted, never used)
  const float* Wlin     = (const float*)d_in[10];
  const float* blin     = (const float*)d_in[11];
  const float* Wu       = (const float*)d_in[12];
  const float* bu       = (const float*)d_in[13];
  const int* esrc       = (const int*)d_in[14];
  const int* edst       = (const int*)d_in[15];
  const int* perm       = (const int*)d_in[16];

  int N = in_sizes[0] / 128;
  int E = in_sizes[14];
  int L = in_sizes[3];
  int n4 = N * 32;
  int nb = (N + 255) / 256;
  float invN = 1.f / (float)N;
  int gemm_grid = (N + 63) / 64;

  // workspace carve-up (Afused fp8 [N][256] aliases featb region)
  char* p = (char*)d_ws;
  size_t off = 0;
  auto take = [&](size_t b) { char* r = p + off; off += (b + 255) & ~(size_t)255; return (void*)r; };
  size_t nb_h = (size_t)N * 128 * sizeof(u16);
  u16*   featb  = (u16*)take(nb_h);       // bf16 features (Bfeat GEMM); later Afused
  u16*   h2b    = (u16*)take(nb_h);       // pre-BN h2 per layer (bf16); later YZ
  u16*   aggb   = (u16*)take(nb_h);       // aggregated rows (bf16, MFMA A)
  u8*    featq  = (u8*)take((size_t)N * 128);        // fp8 features (gather)
  u8*    y1q    = (u8*)take((size_t)N * 128);        // fp8 post-BN1 y1 (gather)
  u8*    Yb     = (u8*)take((size_t)N * 128);        // fp8 y
  u16*   Bfeat  = (u16*)take(nb_h);                  // bf16 B
  u8*    Afused = (u8*)featb;             // [N][256] fp8 interleaved (pos|neg)
  u8*    YZ     = (u8*)h2b;               // [N][256] fp8 interleaved (y|z)
  u16*   Wt     = (u16*)take((size_t)(L + 2) * 16384 * 2);
  int*   cnt    = (int*)take((size_t)N * 4);
  int*   rowptr = (int*)take((size_t)(N + 1) * 4);
  int*   cursor = (int*)take((size_t)N * 4);
  int*   col    = (int*)take((size_t)E * 4);
  int*   dstj   = (int*)take((size_t)E * 4);
  int*   excl   = (int*)take((size_t)N * 4);
  int*   bsum   = (int*)take((size_t)nb * 4);
  int*   boff   = (int*)take((size_t)nb * 4);
  float* pS1    = (float*)take((size_t)128 * gemm_grid * 4);
  float* pQ1    = (float*)take((size_t)128 * gemm_grid * 4);
  float* pS2    = (float*)take((size_t)128 * BNG * 4);
  float* pQ2    = (float*)take((size_t)128 * BNG * 4);
  float* scale1 = (float*)take(512);
  float* shift1 = (float*)take(512);
  float* scale2 = (float*)take(512);
  float* shift2 = (float*)take(512);
  double* acc   = (double*)take(256);
  (void)ws_size; (void)n_in; (void)out_size;

  hipMemsetAsync(cnt, 0, (size_t)N * 4, stream);
  hipMemsetAsync(acc, 0, 16, stream);
  convw<<<((L + 2) * 16384 + 255) / 256, 256, 0, stream>>>(gin_W, Wlin, Wt, L);
  convf<<<2048, 256, 0, stream>>>(features, featb, featq, n4);
  int eg = (E + 255) / 256;
  // CSR: dst -> [src]
  cntk<<<eg, 256, 0, stream>>>(cnt, edst, E);
  scanA<<<nb, 256, 0, stream>>>(cnt, excl, bsum, N);
  scanB<<<1, 256, 0, stream>>>(bsum, boff, nb, rowptr + N);
  scanC<<<nb, 256, 0, stream>>>(excl, boff, rowptr, cursor, N);
  fillk<<<eg, 256, 0, stream>>>(edst, esrc, cursor, col, E);
  sortk<<<(N + 3) / 4, 256, 0, stream>>>(rowptr, col, dstj, N);

  int agg_grid = (N + 15) / 16;
  for (int l = 0; l < L; l++) {
    if (l == 0)
      aggk0<0><<<agg_grid, 256, 0, stream>>>(featq, aggb, rowptr, col, gin_eps, l,
                                             nullptr, nullptr, N);
    else
      aggk0<1><<<agg_grid, 256, 0, stream>>>(y1q, aggb, rowptr, col, gin_eps, l,
                                             scale2, shift2, N);
    gemm_k128<<<gemm_grid, 256, 0, stream>>>(aggb, Wt + (size_t)l * 16384, gin_b + l * 128,
                                             h2b, pS1, pQ1, gemm_grid, 128, 0, 0,
                                             nullptr, nullptr, N);
    finbn<<<128, 256, 0, stream>>>(pS1, pQ1, gemm_grid, gemm_grid,
                                   bn1_g + l * 128, bn1_b + l * 128, scale1, shift1, invN);
    bnmid<<<BNG, 256, 0, stream>>>(h2b, y1q, scale1, shift1, pS2, pQ2, n4);
    finbn<<<128, 256, 0, stream>>>(pS2, pQ2, BNG, BNG,
                                   bn2_g + l * 128, bn2_b + l * 128, scale2, shift2, invN);
  }

  // y = relu(bn2(y1)) @ Wlin_top -> Yb (fp8); B_feat = features @ Wlin_bot + blin (bf16)
  gemm_k128<<<gemm_grid, 256, 0, stream>>>(y1q, Wt + (size_t)L * 16384, nullptr,
                                           Yb, nullptr, nullptr, 0, 128, 2, 2,
                                           scale2, shift2, N);
  gemm_k128<<<gemm_grid, 256, 0, stream>>>(featb, Wt + (size_t)(L + 1) * 16384, blin,
                                           Bfeat, nullptr, nullptr, 0, 128, 0, 0,
                                           nullptr, nullptr, N);
  // YZ = {y | y[perm]} interleaved (h2b region free after layers)
  zk<<<(N * 16 + 255) / 256, 256, 0, stream>>>(Yb, perm, YZ, N);
  // A_pos/A_neg fused gather from YZ (one 16B load/lane/edge; overwrites featb region)
  aggab<<<agg_grid, 256, 0, stream>>>(YZ, Afused, rowptr, col, N);

  edgek<<<4096, 256, 0, stream>>>(Afused, Bfeat, col, dstj, Wu, bu, E, acc);
  fink<<<1, 1, 0, stream>>>(acc, (float*)d_out, E);
}

// Round 18
// 434.897 us; speedup vs baseline: 1.0916x; 1.0916x over previous
//
#include <hip/hip_runtime.h>
#include <hip/hip_bf16.h>
#include <hip/hip_fp16.h>

typedef float f32x4 __attribute__((ext_vector_type(4)));
typedef float f32x2 __attribute__((ext_vector_type(2)));
typedef short s16x8 __attribute__((ext_vector_type(8)));
typedef unsigned short u16;
typedef unsigned char u8;

#define LOG2F 0.6931471805599453f
#define LDA 136   // padded LDS row stride (bf16 elems): 2-way bank alias only (free)
#define BNG 512   // bnmid grid (also its partial count)

__device__ __forceinline__ u16 f2bf(float f) {               // RNE f32->bf16
  unsigned u = __float_as_uint(f);
  u += 0x7fffu + ((u >> 16) & 1u);
  return (u16)(u >> 16);
}
__device__ __forceinline__ float bf2f(u16 h){ return __uint_as_float((unsigned)h << 16); }
__device__ __forceinline__ float bflo(unsigned u){ return __uint_as_float(u << 16); }
__device__ __forceinline__ float bfhi(unsigned u){ return __uint_as_float(u & 0xffff0000u); }

// fp8 e4m3 (OCP on gfx950) pack/unpack via hardware converts
__device__ __forceinline__ void fp8dec(unsigned u, float* a){   // 4 fp8 bytes -> 4 f32
  f32x2 lo = __builtin_amdgcn_cvt_pk_f32_fp8((int)u, false);
  f32x2 hi = __builtin_amdgcn_cvt_pk_f32_fp8((int)u, true);
  a[0] = lo[0]; a[1] = lo[1]; a[2] = hi[0]; a[3] = hi[1];
}
__device__ __forceinline__ unsigned fp8enc4(float a0, float a1, float a2, float a3){
  int r = __builtin_amdgcn_cvt_pk_fp8_f32(a0, a1, 0, false);
  r = __builtin_amdgcn_cvt_pk_fp8_f32(a2, a3, r, true);
  return (unsigned)r;
}
__device__ __forceinline__ u8 fp8enc1(float v){
  return (u8)(__builtin_amdgcn_cvt_pk_fp8_f32(v, v, 0, false) & 0xff);
}
// fast softplus(-s) via hw exp2/log2 (v_exp_f32 = 2^x, v_log_f32 = log2 x)
__device__ __forceinline__ float softplus_neg(float s){
  float e = __builtin_amdgcn_exp2f(-fabsf(s) * 1.442695040888963f);
  return fmaxf(-s, 0.f) + __builtin_amdgcn_logf(1.f + e) * 0.6931471805599453f;
}

// ---- convert+transpose weights to bf16: Wt[m][c][k] = W_m[k][c] ----
__global__ void convw(const float* __restrict__ gW, const float* __restrict__ Wlin,
                      u16* __restrict__ Wt, int L) {
  int idx = blockIdx.x * 256 + threadIdx.x;
  int total = (L + 2) * 16384;
  if (idx >= total) return;
  int m = idx >> 14, rem = idx & 16383, c = rem >> 7, k = rem & 127;
  float v;
  if (m < L)           v = gW[(size_t)m * 16384 + k * 128 + c];
  else if (m == L)     v = Wlin[k * 128 + c];            // top half (root)
  else                 v = Wlin[(128 + k) * 128 + c];    // bottom half (features)
  Wt[idx] = f2bf(v);
}

// features f32 -> bf16 (for GEMM) + fp8 (for gather)
__global__ void convf(const float* __restrict__ in, u16* __restrict__ outb,
                      u8* __restrict__ outq, int n4) {
  int stride = gridDim.x * blockDim.x;
  for (int i = blockIdx.x * blockDim.x + threadIdx.x; i < n4; i += stride) {
    float4 v = ((const float4*)in)[i];
    ushort4 o; o.x = f2bf(v.x); o.y = f2bf(v.y); o.z = f2bf(v.z); o.w = f2bf(v.w);
    ((ushort4*)outb)[i] = o;
    ((unsigned*)outq)[i] = fp8enc4(v.x, v.y, v.z, v.w);
  }
}

// ---------------- CSR build (dst -> list of src), deterministic ----------------
__global__ void cntk(int* __restrict__ cnt, const int* __restrict__ key, int E) {
  int e = blockIdx.x * 256 + threadIdx.x;
  if (e < E) atomicAdd(&cnt[key[e]], 1);
}

__global__ void scanA(const int* __restrict__ cnt, int* __restrict__ excl,
                      int* __restrict__ bsum, int N) {
  __shared__ int tmp[256];
  int i = blockIdx.x * 256 + threadIdx.x;
  int v = (i < N) ? cnt[i] : 0;
  tmp[threadIdx.x] = v;
  __syncthreads();
  for (int off = 1; off < 256; off <<= 1) {
    int t = (threadIdx.x >= off) ? tmp[threadIdx.x - off] : 0;
    __syncthreads();
    tmp[threadIdx.x] += t;
    __syncthreads();
  }
  if (i < N) excl[i] = tmp[threadIdx.x] - v;
  if (threadIdx.x == 255) bsum[blockIdx.x] = tmp[255];
}

__global__ void scanB(const int* __restrict__ bsum, int* __restrict__ boff,
                      int nb, int* __restrict__ rowptrN) {
  __shared__ int tmp[256];
  __shared__ int carry;
  if (threadIdx.x == 0) carry = 0;
  __syncthreads();
  for (int base = 0; base < nb; base += 256) {
    int i = base + threadIdx.x;
    int v = (i < nb) ? bsum[i] : 0;
    tmp[threadIdx.x] = v;
    __syncthreads();
    for (int off = 1; off < 256; off <<= 1) {
      int t = (threadIdx.x >= off) ? tmp[threadIdx.x - off] : 0;
      __syncthreads();
      tmp[threadIdx.x] += t;
      __syncthreads();
    }
    if (i < nb) boff[i] = carry + tmp[threadIdx.x] - v;
    __syncthreads();
    if (threadIdx.x == 255) carry += tmp[255];
    __syncthreads();
  }
  if (threadIdx.x == 0) *rowptrN = carry;
}

__global__ void scanC(const int* __restrict__ excl, const int* __restrict__ boff,
                      int* __restrict__ rowptr, int* __restrict__ cursor, int N) {
  int i = blockIdx.x * 256 + threadIdx.x;
  if (i < N) {
    int r = excl[i] + boff[blockIdx.x];
    rowptr[i] = r; cursor[i] = r;
  }
}

__global__ void fillk(const int* __restrict__ key, const int* __restrict__ val,
                      int* __restrict__ cursor, int* __restrict__ out, int E) {
  int e = blockIdx.x * 256 + threadIdx.x;
  if (e < E) {
    int pos = atomicAdd(&cursor[key[e]], 1);
    out[pos] = val[e];
  }
}

// wave-parallel per-node sort (bitonic in registers) + dstj fill (merged expk)
__global__ __launch_bounds__(256) void sortk(const int* __restrict__ rowptr,
                                             int* __restrict__ arr,
                                             int* __restrict__ dstj, int N) {
  int wave = threadIdx.x >> 6, lane = threadIdx.x & 63;
  int n = blockIdx.x * 4 + wave;
  if (n >= N) return;
  int lo = rowptr[n], hi = rowptr[n + 1];
  int d = hi - lo;
  for (int j = lo + lane; j < hi; j += 64) dstj[j] = n;
  if (d <= 1) return;
  if (d <= 64) {
    int v = (lane < d) ? arr[lo + lane] : 0x7fffffff;
#pragma unroll
    for (int k = 2; k <= 64; k <<= 1) {
#pragma unroll
      for (int jj = k >> 1; jj > 0; jj >>= 1) {
        int partner = __shfl_xor(v, jj);
        bool up = ((lane & k) == 0);
        bool keepmin = (((lane & jj) == 0) == up);
        v = keepmin ? min(v, partner) : max(v, partner);
      }
    }
    if (lane < d) arr[lo + lane] = v;
  } else if (lane == 0) {
    for (int i = lo + 1; i < hi; i++) {
      int v = arr[i];
      int j = i - 1;
      while (j >= lo && arr[j] > v) { arr[j + 1] = arr[j]; j--; }
      arr[j + 1] = v;
    }
  }
}

// YZ[n] = interleaved {y[n] 8B | y[perm[n]] 8B} per lane16 (row 256B), raw fp8 copy
__global__ void zk(const u8* __restrict__ Yb, const int* __restrict__ perm,
                   u8* __restrict__ YZ, int N) {
  int idx = blockIdx.x * 256 + threadIdx.x;
  if (idx >= N * 16) return;
  int n = idx >> 4, l = idx & 15;
  const uint2* y2 = (const uint2*)Yb;
  uint2 a = y2[(size_t)n * 16 + l];
  uint2 b = y2[(size_t)perm[n] * 16 + l];
  uint4 o; o.x = a.x; o.y = a.y; o.z = b.x; o.w = b.y;
  ((uint4*)YZ)[idx] = o;
}

// ---------------- GIN aggregation from fp8 rows (1 node / 16-lane group) ----------
template<int BN>
__global__ __launch_bounds__(256) void aggk0(
    const u8* __restrict__ emb, u16* __restrict__ out,
    const int* __restrict__ rowptr, const int* __restrict__ col,
    const float* __restrict__ epsp, int l,
    const float* __restrict__ sc2, const float* __restrict__ sh2, int N) {
  int tid = threadIdx.x;
  int grp = tid >> 4, lane16 = tid & 15;
  int n = blockIdx.x * 16 + grp;
  if (n >= N) return;
  int lo = rowptr[n], hi = rowptr[n + 1];
  const uint2* embq = (const uint2*)emb;       // row = 16 uint2 (128B)
  float sc[8], sh[8];
  if (BN) {
#pragma unroll
    for (int k = 0; k < 8; k++) { sc[k] = sc2[lane16 * 8 + k]; sh[k] = sh2[lane16 * 8 + k]; }
  }
  float s[8] = {0.f,0.f,0.f,0.f,0.f,0.f,0.f,0.f};
#define ACCD(v) { float t[8]; fp8dec(v.x, t); fp8dec(v.y, t + 4); \
                  _Pragma("unroll") for (int k = 0; k < 8; k++) \
                    s[k] += BN ? fmaxf(fmaf(t[k], sc[k], sh[k]), 0.f) : t[k]; }
  int j = lo;
  for (; j + 4 <= hi; j += 4) {
    int c0 = col[j], c1 = col[j+1], c2 = col[j+2], c3 = col[j+3];
    uint2 v0 = embq[(size_t)c0 * 16 + lane16];
    uint2 v1 = embq[(size_t)c1 * 16 + lane16];
    uint2 v2 = embq[(size_t)c2 * 16 + lane16];
    uint2 v3 = embq[(size_t)c3 * 16 + lane16];
    ACCD(v0); ACCD(v1); ACCD(v2); ACCD(v3);
  }
  for (; j < hi; j++) {
    uint2 v = embq[(size_t)col[j] * 16 + lane16];
    ACCD(v);
  }
#undef ACCD
  float e1 = 1.f + epsp[l];
  {
    uint2 hv = embq[(size_t)n * 16 + lane16];
    float t[8]; fp8dec(hv.x, t); fp8dec(hv.y, t + 4);
#pragma unroll
    for (int k = 0; k < 8; k++) {
      float g = BN ? fmaxf(fmaf(t[k], sc[k], sh[k]), 0.f) : t[k];
      s[k] = fmaf(e1, g, s[k]);
    }
  }
  uint4 o;
  o.x = ((unsigned)f2bf(s[1]) << 16) | (unsigned)f2bf(s[0]);
  o.y = ((unsigned)f2bf(s[3]) << 16) | (unsigned)f2bf(s[2]);
  o.z = ((unsigned)f2bf(s[5]) << 16) | (unsigned)f2bf(s[4]);
  o.w = ((unsigned)f2bf(s[7]) << 16) | (unsigned)f2bf(s[6]);
  ((uint4*)out)[(size_t)n * 16 + lane16] = o;
}

// ---------------- GEMM: out[n][c] = cvt(g(A[n]) @ Wt^T + bias) ----------------
// infmt: 0 bf16 in, 2 fp8 in. optional g(x)=relu(bnsc*x+bnsh). fmt: 0 bf16 out, 2 fp8 out.
__global__ __launch_bounds__(256) void gemm_k128(
    const void* __restrict__ inv, const u16* __restrict__ Wt, const float* __restrict__ bias,
    void* __restrict__ outv, float* __restrict__ pS, float* __restrict__ pQ, int GP,
    int ostride, int infmt, int fmt,
    const float* __restrict__ bnsc, const float* __restrict__ bnsh, int nrows) {
  __shared__ u16 Alds[64 * LDA];
  __shared__ u16 Wlds[128 * LDA];
  int tid = threadIdx.x;
  int r0 = blockIdx.x * 64;
#pragma unroll
  for (int i = 0; i < 8; i++) {
    int idx = tid + i * 256;
    int r = idx >> 4, o = idx & 15;
    uint4 v = *(const uint4*)(Wt + (size_t)r * 128 + o * 8);
    *(uint4*)(&Wlds[r * LDA + o * 8]) = v;
  }
  {
    int o = tid & 15;                 // channel group fixed per thread
    float sc[8], sh[8];
    if (bnsc) {
#pragma unroll
      for (int k = 0; k < 8; k++) { sc[k] = bnsc[o * 8 + k]; sh[k] = bnsh[o * 8 + k]; }
    }
#pragma unroll
    for (int i = 0; i < 4; i++) {
      int idx = tid + i * 256;
      int r = idx >> 4;
      uint4 v;
      if (infmt == 0 && !bnsc) {      // fast path: raw bf16 copy
        if (r0 + r < nrows) v = ((const uint4*)((const u16*)inv + (size_t)(r0 + r) * 128))[o];
        else { v.x = 0; v.y = 0; v.z = 0; v.w = 0; }
      } else {
        float t[8] = {0.f,0.f,0.f,0.f,0.f,0.f,0.f,0.f};
        if (r0 + r < nrows) {
          if (infmt == 0) {
            uint4 b = ((const uint4*)((const u16*)inv + (size_t)(r0 + r) * 128))[o];
            t[0] = bflo(b.x); t[1] = bfhi(b.x); t[2] = bflo(b.y); t[3] = bfhi(b.y);
            t[4] = bflo(b.z); t[5] = bfhi(b.z); t[6] = bflo(b.w); t[7] = bfhi(b.w);
          } else {
            uint2 q = *(const uint2*)((const u8*)inv + (size_t)(r0 + r) * 128 + o * 8);
            fp8dec(q.x, t); fp8dec(q.y, t + 4);
          }
          if (bnsc) {
#pragma unroll
            for (int k = 0; k < 8; k++) t[k] = fmaxf(fmaf(t[k], sc[k], sh[k]), 0.f);
          }
        }
        v.x = ((unsigned)f2bf(t[1]) << 16) | (unsigned)f2bf(t[0]);
        v.y = ((unsigned)f2bf(t[3]) << 16) | (unsigned)f2bf(t[2]);
        v.z = ((unsigned)f2bf(t[5]) << 16) | (unsigned)f2bf(t[4]);
        v.w = ((unsigned)f2bf(t[7]) << 16) | (unsigned)f2bf(t[6]);
      }
      *(uint4*)(&Alds[r * LDA + o * 8]) = v;
    }
  }
  __syncthreads();
  int lane = tid & 63;
  int wv = tid >> 6;
  int cbase = wv * 32;
  int lr = lane & 15;
  int kg = lane >> 4;
  f32x4 acc[4][2] = {};
#pragma unroll
  for (int kc = 0; kc < 4; kc++) {
    int koff = kc * 32 + kg * 8;
    s16x8 a[4], b[2];
#pragma unroll
    for (int rt = 0; rt < 4; rt++)
      a[rt] = *reinterpret_cast<const s16x8*>(&Alds[(rt * 16 + lr) * LDA + koff]);
#pragma unroll
    for (int ct = 0; ct < 2; ct++)
      b[ct] = *reinterpret_cast<const s16x8*>(&Wlds[(cbase + ct * 16 + lr) * LDA + koff]);
#pragma unroll
    for (int rt = 0; rt < 4; rt++)
#pragma unroll
      for (int ct = 0; ct < 2; ct++)
        acc[rt][ct] = __builtin_amdgcn_mfma_f32_16x16x32_bf16(a[rt], b[ct], acc[rt][ct], 0, 0, 0);
  }
#pragma unroll
  for (int ct = 0; ct < 2; ct++) {
    int c = cbase + ct * 16 + lr;
    float bv = bias ? bias[c] : 0.f;
    float ls = 0.f, lq = 0.f;
#pragma unroll
    for (int rt = 0; rt < 4; rt++)
#pragma unroll
      for (int j = 0; j < 4; j++) {
        int row = r0 + rt * 16 + kg * 4 + j;
        if (row < nrows) {
          float v = acc[rt][ct][j] + bv;
          size_t idx = (size_t)row * ostride + c;
          if (fmt == 0)      ((u16*)outv)[idx] = f2bf(v);
          else               ((u8*)outv)[idx] = fp8enc1(v);
          ls += v; lq += v * v;
        }
      }
    if (pS) {
      ls += __shfl_xor(ls, 16); lq += __shfl_xor(lq, 16);
      ls += __shfl_xor(ls, 32); lq += __shfl_xor(lq, 32);
      if (kg == 0) {
        pS[(size_t)c * GP + blockIdx.x] = ls;
        pQ[(size_t)c * GP + blockIdx.x] = lq;
      }
    }
  }
}

// finalize BN params from per-block partials
__global__ __launch_bounds__(256) void finbn(
    const float* __restrict__ pS, const float* __restrict__ pQ, int G, int GP,
    const float* __restrict__ g, const float* __restrict__ b,
    float* __restrict__ scale, float* __restrict__ shift, float invN) {
  int c = blockIdx.x;
  int tid = threadIdx.x;
  float s = 0.f, q = 0.f;
  for (int i = tid; i < G; i += 256) {
    s += pS[(size_t)c * GP + i];
    q += pQ[(size_t)c * GP + i];
  }
  __shared__ float rs[256], rq[256];
  rs[tid] = s; rq[tid] = q;
  __syncthreads();
  for (int off = 128; off > 0; off >>= 1) {
    if (tid < off) { rs[tid] += rs[tid + off]; rq[tid] += rq[tid + off]; }
    __syncthreads();
  }
  if (tid == 0) {
    float m = rs[0] * invN;
    float v = rq[0] * invN - m * m;
    float sc = g[c] * rsqrtf(v + 1e-5f);
    scale[c] = sc;
    shift[c] = b[c] - m * sc;
  }
}

// y1 = fp8(relu(scale1*x+shift1)) + per-block column partials of y1
__global__ __launch_bounds__(256) void bnmid(
    const u16* __restrict__ x, u8* __restrict__ yq,
    const float* __restrict__ scale1, const float* __restrict__ shift1,
    float* __restrict__ pS, float* __restrict__ pQ, int n4) {
  int tid = threadIdx.x;
  int i0 = blockIdx.x * 256 + tid;
  int stride = gridDim.x * 256;
  int c4 = i0 & 31;
  float sc[4], sh[4];
#pragma unroll
  for (int k = 0; k < 4; k++) {
    sc[k] = scale1[c4 * 4 + k];
    sh[k] = shift1[c4 * 4 + k];
  }
  float ls[4] = {0.f,0.f,0.f,0.f}, lq[4] = {0.f,0.f,0.f,0.f};
  for (int i = i0; i < n4; i += stride) {
    ushort4 hv = ((const ushort4*)x)[i];
    float v0 = fmaxf(fmaf(bf2f(hv.x), sc[0], sh[0]), 0.f);
    float v1 = fmaxf(fmaf(bf2f(hv.y), sc[1], sh[1]), 0.f);
    float v2 = fmaxf(fmaf(bf2f(hv.z), sc[2], sh[2]), 0.f);
    float v3 = fmaxf(fmaf(bf2f(hv.w), sc[3], sh[3]), 0.f);
    ((unsigned*)yq)[i] = fp8enc4(v0, v1, v2, v3);
    ls[0] += v0; ls[1] += v1; ls[2] += v2; ls[3] += v3;
    lq[0] += v0*v0; lq[1] += v1*v1; lq[2] += v2*v2; lq[3] += v3*v3;
  }
  __shared__ float red[256][8];
#pragma unroll
  for (int k = 0; k < 4; k++) { red[tid][k] = ls[k]; red[tid][4+k] = lq[k]; }
  __syncthreads();
  for (int off = 128; off >= 32; off >>= 1) {
    if (tid < off)
#pragma unroll
      for (int s = 0; s < 8; s++) red[tid][s] += red[tid + off][s];
    __syncthreads();
  }
  if (tid < 32) {
#pragma unroll
    for (int k = 0; k < 4; k++) {
      pS[(size_t)(tid * 4 + k) * BNG + blockIdx.x] = red[tid][k];
      pQ[(size_t)(tid * 4 + k) * BNG + blockIdx.x] = red[tid][4 + k];
    }
  }
}

// Af[n] = interleaved {pos 8B | neg 8B} per lane16 (row 256B), fp8.
// ONE 16B load/lane/edge from interleaved YZ; 4-edge unroll.
__global__ __launch_bounds__(256) void aggab(
    const u8* __restrict__ YZ, u8* __restrict__ Af,
    const int* __restrict__ rowptr, const int* __restrict__ col, int N) {
  int tid = threadIdx.x;
  int grp = tid >> 4, lane16 = tid & 15;
  int n = blockIdx.x * 16 + grp;
  if (n >= N) return;
  int lo = rowptr[n], hi = rowptr[n + 1];
  const uint4* yz = (const uint4*)YZ;          // row = 16 uint4 (y8|z8 per lane)
  uint4* af = (uint4*)Af;
  if (hi == lo) {                              // deg 0: {y[n], y[perm[n]]} = YZ row
    af[(size_t)n * 16 + lane16] = yz[(size_t)n * 16 + lane16];
    return;
  }
  float ap[8] = {0.f,0.f,0.f,0.f,0.f,0.f,0.f,0.f};
  float an[8] = {0.f,0.f,0.f,0.f,0.f,0.f,0.f,0.f};
#define ACCD(v) { float t[8], u[8]; \
                  fp8dec(v.x, t); fp8dec(v.y, t + 4); \
                  fp8dec(v.z, u); fp8dec(v.w, u + 4); \
                  _Pragma("unroll") for (int k = 0; k < 8; k++) { ap[k] += t[k]; an[k] += u[k]; } }
  int j = lo;
  for (; j + 4 <= hi; j += 4) {
    int c0 = col[j], c1 = col[j+1], c2 = col[j+2], c3 = col[j+3];
    uint4 v0 = yz[(size_t)c0 * 16 + lane16];
    uint4 v1 = yz[(size_t)c1 * 16 + lane16];
    uint4 v2 = yz[(size_t)c2 * 16 + lane16];
    uint4 v3 = yz[(size_t)c3 * 16 + lane16];
    ACCD(v0); ACCD(v1); ACCD(v2); ACCD(v3);
  }
  for (; j < hi; j++) {
    uint4 v = yz[(size_t)col[j] * 16 + lane16];
    ACCD(v);
  }
#undef ACCD
  float inv = 1.f / (float)(hi - lo);
  uint4 o;
  o.x = fp8enc4(ap[0]*inv, ap[1]*inv, ap[2]*inv, ap[3]*inv);
  o.y = fp8enc4(ap[4]*inv, ap[5]*inv, ap[6]*inv, ap[7]*inv);
  o.z = fp8enc4(an[0]*inv, an[1]*inv, an[2]*inv, an[3]*inv);
  o.w = fp8enc4(an[4]*inv, an[5]*inv, an[6]*inv, an[7]*inv);
  af[(size_t)n * 16 + lane16] = o;
}

// flat dst-major edge scoring: 16 lanes/edge, 4-edge unroll, f32 math;
// Af[src] interleaved fp8 = ONE 16B load/lane; B[dst] bf16 = ONE 16B load
__global__ __launch_bounds__(256) void edgek(
    const u8* __restrict__ Af, const u16* __restrict__ Bf,
    const int* __restrict__ col, const int* __restrict__ dstj,
    const float* __restrict__ Wu, const float* __restrict__ bu,
    int E, double* __restrict__ acc) {
  int tid = threadIdx.x;
  int lane16 = tid & 15;
  float w[8];
#pragma unroll
  for (int k = 0; k < 8; k++) w[k] = Wu[lane16 * 8 + k];
  float bias = bu[0];
  float lp = 0.f, ln = 0.f;
  int g = (blockIdx.x * 256 + tid) >> 4;
  int ng = (gridDim.x * 256) >> 4;
  int per = (E + ng - 1) / ng;
  int j0 = g * per;
  int j1 = min(E, j0 + per);
#define EDGE(jj, SP, SN) { \
    int s = col[jj]; int d = dstj[jj]; \
    uint4 av = *(const uint4*)(Af + (size_t)s * 256 + lane16 * 16); \
    uint4 bv = *(const uint4*)(Bf + (size_t)d * 128 + lane16 * 8); \
    float a8[8], n8[8]; \
    fp8dec(av.x, a8); fp8dec(av.y, a8 + 4); \
    fp8dec(av.z, n8); fp8dec(av.w, n8 + 4); \
    float bb[8] = {bflo(bv.x), bfhi(bv.x), bflo(bv.y), bfhi(bv.y), \
                   bflo(bv.z), bfhi(bv.z), bflo(bv.w), bfhi(bv.w)}; \
    _Pragma("unroll") \
    for (int i = 0; i < 8; i++) { \
      SP = fmaf(fmaxf(a8[i] + bb[i], 0.f), w[i], SP); \
      SN = fmaf(fmaxf(n8[i] + bb[i], 0.f), w[i], SN); \
    } }
  int j = j0;
  for (; j + 4 <= j1; j += 4) {
    float sp0 = 0.f, sn0 = 0.f, sp1 = 0.f, sn1 = 0.f;
    float sp2 = 0.f, sn2 = 0.f, sp3 = 0.f, sn3 = 0.f;
    EDGE(j, sp0, sn0);
    EDGE(j + 1, sp1, sn1);
    EDGE(j + 2, sp2, sn2);
    EDGE(j + 3, sp3, sn3);
#pragma unroll
    for (int m = 1; m < 16; m <<= 1) {
      sp0 += __shfl_xor(sp0, m); sn0 += __shfl_xor(sn0, m);
      sp1 += __shfl_xor(sp1, m); sn1 += __shfl_xor(sn1, m);
      sp2 += __shfl_xor(sp2, m); sn2 += __shfl_xor(sn2, m);
      sp3 += __shfl_xor(sp3, m); sn3 += __shfl_xor(sn3, m);
    }
    if (lane16 == 0) {
      float a0 = sp0 + bias, b0 = sn0 + bias;
      float a1 = sp1 + bias, b1 = sn1 + bias;
      float a2 = sp2 + bias, b2 = sn2 + bias;
      float a3 = sp3 + bias, b3 = sn3 + bias;
      lp += (LOG2F - softplus_neg(a0)) + (LOG2F - softplus_neg(a1))
          + (LOG2F - softplus_neg(a2)) + (LOG2F - softplus_neg(a3));
      ln += (softplus_neg(b0) + b0 - LOG2F) + (softplus_neg(b1) + b1 - LOG2F)
          + (softplus_neg(b2) + b2 - LOG2F) + (softplus_neg(b3) + b3 - LOG2F);
    }
  }
  for (; j < j1; j++) {
    float sp = 0.f, sn = 0.f;
    EDGE(j, sp, sn);
#pragma unroll
    for (int m = 1; m < 16; m <<= 1) {
      sp += __shfl_xor(sp, m); sn += __shfl_xor(sn, m);
    }
    if (lane16 == 0) {
      float a = sp + bias, b = sn + bias;
      lp += LOG2F - softplus_neg(a);
      ln += softplus_neg(b) + b - LOG2F;
    }
  }
#undef EDGE
  __shared__ float rp[256], rn[256];
  rp[tid] = lp; rn[tid] = ln;
  __syncthreads();
  for (int off = 128; off > 0; off >>= 1) {
    if (tid < off) { rp[tid] += rp[tid + off]; rn[tid] += rn[tid + off]; }
    __syncthreads();
  }
  if (tid == 0) {
    unsafeAtomicAdd(&acc[0], (double)rp[0]);
    unsafeAtomicAdd(&acc[1], (double)rn[0]);
  }
}

__global__ void fink(const double* __restrict__ acc, float* __restrict__ out, int E) {
  out[0] = (float)((acc[1] - acc[0]) / (double)E);
}

extern "C" void kernel_launch(void* const* d_in, const int* in_sizes, int n_in,
                              void* d_out, int out_size, void* d_ws, size_t ws_size,
                              hipStream_t stream) {
  const float* features = (const float*)d_in[0];
  const float* gin_W    = (const float*)d_in[1];
  const float* gin_b    = (const float*)d_in[2];
  const float* gin_eps  = (const float*)d_in[3];
  const float* bn1_g    = (const float*)d_in[4];
  const float* bn1_b    = (const float*)d_in[5];
  const float* bn2_g    = (const float*)d_in[6];
  const float* bn2_b    = (const float*)d_in[7];
  // d_in[8]=Wz, d_in[9]=bz: dead code in reference (m1 deleted, never used)
  const float* Wlin     = (const float*)d_in[10];
  const float* blin     = (const float*)d_in[11];
  const float* Wu       = (const float*)d_in[12];
  const float* bu       = (const float*)d_in[13];
  const int* esrc       = (const int*)d_in[14];
  const int* edst       = (const int*)d_in[15];
  const int* perm       = (const int*)d_in[16];

  int N = in_sizes[0] / 128;
  int E = in_sizes[14];
  int L = in_sizes[3];
  int n4 = N * 32;
  int nb = (N + 255) / 256;
  float invN = 1.f / (float)N;
  int gemm_grid = (N + 63) / 64;

  // workspace carve-up (Afused fp8 [N][256] aliases featb region)
  char* p = (char*)d_ws;
  size_t off = 0;
  auto take = [&](size_t b) { char* r = p + off; off += (b + 255) & ~(size_t)255; return (void*)r; };
  size_t nb_h = (size_t)N * 128 * sizeof(u16);
  u16*   featb  = (u16*)take(nb_h);       // bf16 features (Bfeat GEMM); later Afused
  u16*   h2b    = (u16*)take(nb_h);       // pre-BN h2 per layer (bf16); later YZ
  u16*   aggb   = (u16*)take(nb_h);       // aggregated rows (bf16, MFMA A)
  u8*    featq  = (u8*)take((size_t)N * 128);        // fp8 features (gather)
  u8*    y1q    = (u8*)take((size_t)N * 128);        // fp8 post-BN1 y1 (gather)
  u8*    Yb     = (u8*)take((size_t)N * 128);        // fp8 y
  u16*   Bfeat  = (u16*)take(nb_h);                  // bf16 B
  u8*    Afused = (u8*)featb;             // [N][256] fp8 interleaved (pos|neg)
  u8*    YZ     = (u8*)h2b;               // [N][256] fp8 interleaved (y|z)
  u16*   Wt     = (u16*)take((size_t)(L + 2) * 16384 * 2);
  int*   cnt    = (int*)take((size_t)N * 4);
  int*   rowptr = (int*)take((size_t)(N + 1) * 4);
  int*   cursor = (int*)take((size_t)N * 4);
  int*   col    = (int*)take((size_t)E * 4);
  int*   dstj   = (int*)take((size_t)E * 4);
  int*   excl   = (int*)take((size_t)N * 4);
  int*   bsum   = (int*)take((size_t)nb * 4);
  int*   boff   = (int*)take((size_t)nb * 4);
  float* pS1    = (float*)take((size_t)128 * gemm_grid * 4);
  float* pQ1    = (float*)take((size_t)128 * gemm_grid * 4);
  float* pS2    = (float*)take((size_t)128 * BNG * 4);
  float* pQ2    = (float*)take((size_t)128 * BNG * 4);
  float* scale1 = (float*)take(512);
  float* shift1 = (float*)take(512);
  float* scale2 = (float*)take(512);
  float* shift2 = (float*)take(512);
  double* acc   = (double*)take(256);
  (void)ws_size; (void)n_in; (void)out_size;

  hipMemsetAsync(cnt, 0, (size_t)N * 4, stream);
  hipMemsetAsync(acc, 0, 16, stream);
  convw<<<((L + 2) * 16384 + 255) / 256, 256, 0, stream>>>(gin_W, Wlin, Wt, L);
  convf<<<2048, 256, 0, stream>>>(features, featb, featq, n4);
  int eg = (E + 255) / 256;
  // CSR: dst -> [src]
  cntk<<<eg, 256, 0, stream>>>(cnt, edst, E);
  scanA<<<nb, 256, 0, stream>>>(cnt, excl, bsum, N);
  scanB<<<1, 256, 0, stream>>>(bsum, boff, nb, rowptr + N);
  scanC<<<nb, 256, 0, stream>>>(excl, boff, rowptr, cursor, N);
  fillk<<<eg, 256, 0, stream>>>(edst, esrc, cursor, col, E);
  sortk<<<(N + 3) / 4, 256, 0, stream>>>(rowptr, col, dstj, N);

  int agg_grid = (N + 15) / 16;
  for (int l = 0; l < L; l++) {
    if (l == 0)
      aggk0<0><<<agg_grid, 256, 0, stream>>>(featq, aggb, rowptr, col, gin_eps, l,
                                             nullptr, nullptr, N);
    else
      aggk0<1><<<agg_grid, 256, 0, stream>>>(y1q, aggb, rowptr, col, gin_eps, l,
                                             scale2, shift2, N);
    gemm_k128<<<gemm_grid, 256, 0, stream>>>(aggb, Wt + (size_t)l * 16384, gin_b + l * 128,
                                             h2b, pS1, pQ1, gemm_grid, 128, 0, 0,
                                             nullptr, nullptr, N);
    finbn<<<128, 256, 0, stream>>>(pS1, pQ1, gemm_grid, gemm_grid,
                                   bn1_g + l * 128, bn1_b + l * 128, scale1, shift1, invN);
    bnmid<<<BNG, 256, 0, stream>>>(h2b, y1q, scale1, shift1, pS2, pQ2, n4);
    finbn<<<128, 256, 0, stream>>>(pS2, pQ2, BNG, BNG,
                                   bn2_g + l * 128, bn2_b + l * 128, scale2, shift2, invN);
  }

  // y = relu(bn2(y1)) @ Wlin_top -> Yb (fp8); B_feat = features @ Wlin_bot + blin (bf16)
  gemm_k128<<<gemm_grid, 256, 0, stream>>>(y1q, Wt + (size_t)L * 16384, nullptr,
                                           Yb, nullptr, nullptr, 0, 128, 2, 2,
                                           scale2, shift2, N);
  gemm_k128<<<gemm_grid, 256, 0, stream>>>(featb, Wt + (size_t)(L + 1) * 16384, blin,
                                           Bfeat, nullptr, nullptr, 0, 128, 0, 0,
                                           nullptr, nullptr, N);
  // YZ = {y | y[perm]} interleaved (h2b region free after layers)
  zk<<<(N * 16 + 255) / 256, 256, 0, stream>>>(Yb, perm, YZ, N);
  // A_pos/A_neg fused gather from YZ (one 16B load/lane/edge; overwrites featb region)
  aggab<<<agg_grid, 256, 0, stream>>>(YZ, Afused, rowptr, col, N);

  edgek<<<2048, 256, 0, stream>>>(Afused, Bfeat, col, dstj, Wu, bu, E, acc);
  fink<<<1, 1, 0, stream>>>(acc, (float*)d_out, E);
}